// Round 11
// baseline (530.413 us; speedup 1.0000x reference)
//
#include <hip/hip_runtime.h>

#define TT 32

// ---------- bf16 helpers (OCP bfloat16, RNE) ----------
__device__ __forceinline__ float bf16_bits_to_f32(unsigned short u) {
    unsigned v = ((unsigned)u) << 16; float f; __builtin_memcpy(&f, &v, 4); return f;
}
__device__ __forceinline__ unsigned short f32_to_bf16_rne(float f) {
    unsigned u; __builtin_memcpy(&u, &f, 4);
    u += 0x7FFFu + ((u >> 16) & 1u);            // round-to-nearest-even
    return (unsigned short)(u >> 16);
}
__device__ __forceinline__ float round_bf16_f32(float f) {  // f32 -> bf16 -> f32 value
    return bf16_bits_to_f32(f32_to_bf16_rne(f));
}
// Correctly-rounded f64 -> bf16 (single rounding): round-to-odd to f32, then RNE.
__device__ __forceinline__ float f64_to_bf16_f32(double d) {
    float fz = __double2float_rz(d);
    if ((double)fz != d) {
        unsigned u; __builtin_memcpy(&u, &fz, 4); u |= 1u; __builtin_memcpy(&fz, &u, 4);
    }
    return round_bf16_f32(fz);
}
// Spread the 8 bits of b to positions 0,4,8,...,28 (Morton-4).
__device__ __forceinline__ unsigned spread4(unsigned b) {
    unsigned x = (b | (b << 12)) & 0x000F000Fu;
    x = (x | (x << 6)) & 0x03030303u;
    x = (x | (x << 3)) & 0x11111111u;
    return x;
}
// Wave-uniform weight load (scalar path): 2*w as f64. bf16 read via aligned
// u32 (SMEM has no sub-dword loads); wi is wave-uniform -> s_load + s_* ops.
__device__ __forceinline__ double load_w2(const void* wptr, bool isbf, int wi) {
    float wraw;
    if (isbf) {
        const unsigned pair = ((const unsigned*)wptr)[wi >> 1];
        const unsigned short u = (wi & 1) ? (unsigned short)(pair >> 16)
                                          : (unsigned short)(pair & 0xFFFFu);
        wraw = bf16_bits_to_f32(u);
    } else {
        wraw = ((const float*)wptr)[wi];
    }
    return 2.0 * (double)wraw;                   // weight_scale=2 folded (exact)
}

// ---------- dtype detect + init ----------
__global__ void detect_and_init(const unsigned* __restrict__ spk,
                                int* __restrict__ flag, float* __restrict__ sums)
{
    unsigned w = spk[threadIdx.x];
    bool ok = (w == 0u) || (w == 0x3F800000u);
    unsigned long long vote = __ballot(ok);
    if (threadIdx.x == 0) {
        flag[0] = (vote == 0xFFFFFFFFFFFFFFFFull) ? 0 : 1;  // 0=f32, 1=bf16
        sums[0] = 0.f; sums[1] = 0.f; sums[2] = 0.f;
    }
}

// ---------- layer-0: pack spikes into SoA 4-bit index planes ----------
// Word (q, n,g,site): nibble j = spike bits of t=8q+j across the 4 cins of g.
__global__ __launch_bounds__(256)
void pack_interleave(const void* __restrict__ ginv, unsigned* __restrict__ idx0,
                     const int* __restrict__ flag)
{
    const int gid = blockIdx.x * 256 + threadIdx.x;   // 4*32*256 = 32768
    if (gid >= 32768) return;
    const int site = gid & 255;
    const int g    = (gid >> 8) & 31;
    const int n    = gid >> 13;

    unsigned m[4];
    #pragma unroll
    for (int k = 0; k < 4; ++k) {
        const size_t ebase = ((size_t)(n * 128 + 4 * g + k) * 256 + site) * TT;
        unsigned mask = 0u;
        if (flag[0]) {
            const uint4* p = (const uint4*)((const unsigned short*)ginv + ebase);
            #pragma unroll
            for (int q = 0; q < 4; ++q) {
                uint4 a = p[q];
                unsigned wd[4] = {a.x, a.y, a.z, a.w};
                #pragma unroll
                for (int mm = 0; mm < 4; ++mm) {
                    const int t = q * 8 + mm * 2;
                    mask |= (wd[mm] & 0xFFFFu) ? (1u << t)       : 0u;
                    mask |= (wd[mm] >> 16)     ? (1u << (t + 1)) : 0u;
                }
            }
        } else {
            const float4* p = (const float4*)((const float*)ginv + ebase);
            #pragma unroll
            for (int j = 0; j < 8; ++j) {
                float4 v = p[j];
                mask |= (v.x != 0.f) ? (1u << (j * 4 + 0)) : 0u;
                mask |= (v.y != 0.f) ? (1u << (j * 4 + 1)) : 0u;
                mask |= (v.z != 0.f) ? (1u << (j * 4 + 2)) : 0u;
                mask |= (v.w != 0.f) ? (1u << (j * 4 + 3)) : 0u;
            }
        }
        m[k] = mask;
    }
    #pragma unroll
    for (int q = 0; q < 4; ++q) {
        const unsigned w =  spread4((m[0] >> (8 * q)) & 0xFFu)
                         | (spread4((m[1] >> (8 * q)) & 0xFFu) << 1)
                         | (spread4((m[2] >> (8 * q)) & 0xFFu) << 2)
                         | (spread4((m[3] >> (8 * q)) & 0xFFu) << 3);
        idx0[q * 32768 + gid] = w;
    }
}

// ---------- mid-layer: masks -> SoA 4-bit index planes (plain stores) ----------
template<int C, int PLANE>   // C = channels at this interface
__global__ __launch_bounds__(256)
void pack_mid(const unsigned* __restrict__ masks, unsigned* __restrict__ idx)
{
    constexpr int G = C / 4;
    constexpr int TOT = 4 * G * PLANE;
    const int gid = blockIdx.x * 256 + threadIdx.x;
    if (gid >= TOT) return;
    const int site = gid % PLANE;
    const int g    = (gid / PLANE) % G;
    const int n    = gid / (PLANE * G);
    unsigned m[4];
    #pragma unroll
    for (int k = 0; k < 4; ++k)
        m[k] = masks[(n * C + 4 * g + k) * PLANE + site];
    #pragma unroll
    for (int q = 0; q < 4; ++q) {
        const unsigned w =  spread4((m[0] >> (8 * q)) & 0xFFu)
                         | (spread4((m[1] >> (8 * q)) & 0xFFu) << 1)
                         | (spread4((m[2] >> (8 * q)) & 0xFFu) << 2)
                         | (spread4((m[3] >> (8 * q)) & 0xFFu) << 3);
        idx[q * TOT + gid] = w;
    }
}

// ---------- L1/L2: fused ConvT(stride2,k3,pad1, w*2) + CUBA scan ----------
// R10 structure + hybrid pipe routing: per (g,tap) word, j=0..5 go through the
// LDS LUT (broadcast ds_read_b64), j=6,7 are computed on the VALU with
// wave-uniform scalar weights (order w0->w1->w2->w3 with +0.0 no-ops == the
// LUT's sequential construction order -> f64 result bit-identical).
template<int CIN, int COUT>
__global__ __launch_bounds__(256, 4)
void cuba_layer(const unsigned* __restrict__ idxIn, const void* __restrict__ wptr,
                unsigned* __restrict__ maskOut, int N, int Hi, int Wi,
                float* __restrict__ sumOut, const int* __restrict__ flag)
{
    constexpr int G = CIN / 4;
    const bool isbf = (flag[0] != 0);
    const int Ho = 2 * Hi - 1, Wo = 2 * Wi - 1;
    const int co = (int)blockIdx.y;
    const int zz = 3 - (int)blockIdx.z;          // heavy class first
    const int po = zz >> 1, pw = zz & 1;
    const int lg = po + pw;
    const int nTap = 1 << lg;
    const int nH = Hi - po, nW = Wi - pw;
    const int sites = N * nH * nW;               // sites in this class (per co)
    const int siteBase = (int)blockIdx.x * 256;
    if (siteBase >= sites) return;               // dead block (uniform)

    // LUT[group][tap][idx]: sequential f64 sum of selected 2*w over the 4 cins.
    __shared__ double lut[G][4][16];
    {
        const unsigned short* w16 = (const unsigned short*)wptr;
        const float* w32 = (const float*)wptr;
        const int entries = G * nTap * 16;
        for (int e = threadIdx.x; e < entries; e += 256) {
            const int idx = e & 15;
            const int tp  = (e >> 4) & (nTap - 1);
            const int g   = e >> (4 + lg);
            const int v = (po && (tp >= (pw ? 2 : 1))) ? 1 : 0;
            const int h = pw ? (tp & 1) : 0;
            const int kh = v ? 0 : (po ? 2 : 1);
            const int kw = h ? 0 : (pw ? 2 : 1);
            const int wof = kh * 3 + kw;
            double s = 0.0;
            #pragma unroll
            for (int k = 0; k < 4; ++k) {
                if ((idx >> k) & 1) {
                    const int wi = ((4 * g + k) * COUT + co) * 9 + wof;
                    const float wraw = isbf ? bf16_bits_to_f32(w16[wi]) : w32[wi];
                    s += 2.0 * (double)wraw;
                }
            }
            lut[g][tp][idx] = s;
        }
    }
    __syncthreads();

    const int siteIdx = siteBase + (int)threadIdx.x;
    float cnt = 0.f;

    if (siteIdx < sites) {
        const int b  = siteIdx % nW;
        const int t1 = siteIdx / nW;
        const int a  = t1 % nH;
        const int n  = t1 / nH;
        const int oh = 2 * a + po, ow = 2 * b + pw;
        const int plane = Hi * Wi;
        const int QT = N * G * plane;            // words per q-plane

        const int siteA = a * Wi + b;
        const int siteB = siteA + 1;
        const int siteC = siteA + Wi;
        const int siteD = siteC + 1;
        const int khA = po ? 2 : 1, kwA = pw ? 2 : 1;
        const int wofA = khA * 3 + kwA;          // tap -> weight offset
        const int wofB = khA * 3;
        const int wofC = kwA;

        unsigned mask = 0u;
        float  curF = 0.f, volF = 0.f;
        double curD = 0.0, volD = 0.0;

        #pragma unroll 1
        for (int p = 0; p < 4; ++p) {
            double acc[8];
            #pragma unroll
            for (int j = 0; j < 8; ++j) acc[j] = 0.0;

            const unsigned* pb = idxIn + (size_t)p * QT + (size_t)(n * G) * plane;

            // Prefetch g=0 idx words.
            unsigned wA = pb[siteA];
            unsigned wB = pw ? pb[siteB] : 0u;
            unsigned wC = po ? pb[siteC] : 0u;
            unsigned wD = (po && pw) ? pb[siteD] : 0u;

            #pragma unroll 1
            for (int g = 0; g < G; ++g) {
                // Issue next-g loads before consuming current words.
                const unsigned* bpn = pb + (size_t)((g + 1 < G) ? g + 1 : g) * plane;
                const unsigned nA = bpn[siteA];
                const unsigned nB = pw ? bpn[siteB] : 0u;
                const unsigned nC = po ? bpn[siteC] : 0u;
                const unsigned nD = (po && pw) ? bpn[siteD] : 0u;

                auto tapWork = [&](unsigned w, int tp, int wof) {
                    #pragma unroll
                    for (int j = 0; j < 6; ++j)
                        acc[j] += lut[g][tp][(w >> (4 * j)) & 0xFu];
                    // j=6,7 on the VALU with wave-uniform scalar weights.
                    const int wb = (4 * g * COUT + co) * 9 + wof;
                    const double w0 = load_w2(wptr, isbf, wb);
                    const double w1 = load_w2(wptr, isbf, wb + COUT * 9);
                    const double w2 = load_w2(wptr, isbf, wb + 2 * COUT * 9);
                    const double w3 = load_w2(wptr, isbf, wb + 3 * COUT * 9);
                    acc[6] += (w & (1u << 24)) ? w0 : 0.0;
                    acc[6] += (w & (1u << 25)) ? w1 : 0.0;
                    acc[6] += (w & (1u << 26)) ? w2 : 0.0;
                    acc[6] += (w & (1u << 27)) ? w3 : 0.0;
                    acc[7] += (w & (1u << 28)) ? w0 : 0.0;
                    acc[7] += (w & (1u << 29)) ? w1 : 0.0;
                    acc[7] += (w & (1u << 30)) ? w2 : 0.0;
                    acc[7] += (w & (1u << 31)) ? w3 : 0.0;
                };

                tapWork(wA, 0, wofA);
                if (pw) tapWork(wB, 1, wofB);    // block-uniform branches
                if (po) {
                    tapWork(wC, pw ? 2 : 1, wofC);
                    if (pw) tapWork(wD, 3, 0);
                }

                wA = nA; wB = nB; wC = nC; wD = nD;
            }

            // CUBA scan, 8 steps with carried state.
            if (isbf) {
                #pragma unroll
                for (int j = 0; j < 8; ++j) {
                    const int t = p * 8 + j;
                    const float z = f64_to_bf16_f32(acc[j]);
                    curF = round_bf16_f32(0.5f * curF + z);
                    volF = round_bf16_f32(0.5f * volF + curF);
                    const bool fire = (volF >= 1.0f);
                    mask |= fire ? (1u << t) : 0u;
                    volF = fire ? 0.f : volF;
                }
            } else {
                #pragma unroll
                for (int j = 0; j < 8; ++j) {
                    const int t = p * 8 + j;
                    curD = fma(0.5, curD, acc[j]);
                    volD = fma(0.5, volD, curD);
                    const bool fire = (volD >= 1.0);
                    mask |= fire ? (1u << t) : 0u;
                    volD = fire ? 0.0 : volD;
                }
            }
        }
        cnt = (float)__popc(mask);
        maskOut[((n * COUT + co) * Ho + oh) * Wo + ow] = mask;
    }

    // Wave-level (64) count reduction; per-layer sums are integers < 2^24 so
    // fp32 atomic accumulation is exact.
    #pragma unroll
    for (int o = 32; o >= 1; o >>= 1) cnt += __shfl_down(cnt, o);
    if ((threadIdx.x & 63) == 0 && cnt > 0.f) atomicAdd(sumOut, cnt);
}

// ---------- L3: tap-slab kernel (S = nTap slabs, LDS combine) + hybrid ----------
template<int CIN, int COUT>
__global__ __launch_bounds__(256)
void cuba_layer_slab(const unsigned* __restrict__ idxIn, const void* __restrict__ wptr,
                     void* __restrict__ goutv, int N, int Hi, int Wi,
                     float* __restrict__ sumOut, const int* __restrict__ flag)
{
    constexpr int G = CIN / 4;
    const bool isbf = (flag[0] != 0);
    const int Ho = 2 * Hi - 1, Wo = 2 * Wi - 1;
    const int co = (int)blockIdx.y;
    const int zz = 3 - (int)blockIdx.z;          // heavy class first
    const int po = zz >> 1, pw = zz & 1;
    const int lg = po + pw;
    const int nTap = 1 << lg;
    const int nH = Hi - po, nW = Wi - pw;
    const int sites = N * nH * nW;
    const int lS = lg;
    const int S  = 1 << lS;                      // slabs per block (== nTap)
    const int spb = 256 >> lS;                   // sites per block
    const int siteBase = (int)blockIdx.x * spb;
    if (siteBase >= sites) return;               // dead block (uniform)

    __shared__ double lut[G][4][16];
    __shared__ double xch[1536];                 // slab-partial exchange
    {
        const unsigned short* w16 = (const unsigned short*)wptr;
        const float* w32 = (const float*)wptr;
        const int entries = G * nTap * 16;
        for (int e = threadIdx.x; e < entries; e += 256) {
            const int idx = e & 15;
            const int tp  = (e >> 4) & (nTap - 1);
            const int g   = e >> (4 + lg);
            const int v = (po && (tp >= (pw ? 2 : 1))) ? 1 : 0;
            const int h = pw ? (tp & 1) : 0;
            const int kh = v ? 0 : (po ? 2 : 1);
            const int kw = h ? 0 : (pw ? 2 : 1);
            const int wof = kh * 3 + kw;
            double s = 0.0;
            #pragma unroll
            for (int k = 0; k < 4; ++k) {
                if ((idx >> k) & 1) {
                    const int wi = ((4 * g + k) * COUT + co) * 9 + wof;
                    const float wraw = isbf ? bf16_bits_to_f32(w16[wi]) : w32[wi];
                    s += 2.0 * (double)wraw;
                }
            }
            lut[g][tp][idx] = s;
        }
    }
    __syncthreads();

    const int slab = (int)threadIdx.x >> (8 - lS);
    const int sl   = (int)threadIdx.x & (spb - 1);
    const int siteIdx = siteBase + sl;
    const bool valid = siteIdx < sites;
    const int sIdx = valid ? siteIdx : 0;        // clamp for safe addresses

    const int b  = sIdx % nW;
    const int t1v = sIdx / nW;
    const int a  = t1v % nH;
    const int n  = t1v / nH;
    const int oh = 2 * a + po, ow = 2 * b + pw;
    const int plane = Hi * Wi;
    const int QT = N * G * plane;                // words per q-plane (SoA)

    const int siteA = a * Wi + b;
    const int siteB = siteA + 1;
    const int siteC = siteA + Wi;
    const int siteD = siteC + 1;
    const int khA = po ? 2 : 1, kwA = pw ? 2 : 1;

    // Per-thread tap assignment (wave-uniform).
    int s1 = siteA, tp1 = 0, wof1 = khA * 3 + kwA;
    if (zz == 1)      { if (slab == 1) { s1 = siteB; tp1 = 1; wof1 = khA * 3; } }
    else if (zz == 2) { if (slab == 1) { s1 = siteC; tp1 = 1; wof1 = kwA; } }
    else if (zz == 3) {
        if      (slab == 1) { s1 = siteB; tp1 = 1; wof1 = khA * 3; }
        else if (slab == 2) { s1 = siteC; tp1 = 2; wof1 = kwA; }
        else if (slab == 3) { s1 = siteD; tp1 = 3; wof1 = 0; }
    }

    unsigned mask = 0u;
    float  curF = 0.f, volF = 0.f;
    double curD = 0.0, volD = 0.0;
    float cnt = 0.f;

    #pragma unroll 1
    for (int p = 0; p < 4; ++p) {
        double acc[8];
        #pragma unroll
        for (int j = 0; j < 8; ++j) acc[j] = 0.0;

        const unsigned* pb = idxIn + (size_t)p * QT + (size_t)(n * G) * plane;

        unsigned w1 = pb[s1];                    // prefetch g=0
        #pragma unroll 1
        for (int g = 0; g < G; ++g) {
            const unsigned nw =
                pb[(size_t)((g + 1 < G) ? g + 1 : g) * plane + s1];
            #pragma unroll
            for (int j = 0; j < 6; ++j)
                acc[j] += lut[g][tp1][(w1 >> (4 * j)) & 0xFu];
            const int wb = (4 * g * COUT + co) * 9 + wof1;
            const double v0 = load_w2(wptr, isbf, wb);
            const double v1 = load_w2(wptr, isbf, wb + COUT * 9);
            const double v2 = load_w2(wptr, isbf, wb + 2 * COUT * 9);
            const double v3 = load_w2(wptr, isbf, wb + 3 * COUT * 9);
            acc[6] += (w1 & (1u << 24)) ? v0 : 0.0;
            acc[6] += (w1 & (1u << 25)) ? v1 : 0.0;
            acc[6] += (w1 & (1u << 26)) ? v2 : 0.0;
            acc[6] += (w1 & (1u << 27)) ? v3 : 0.0;
            acc[7] += (w1 & (1u << 28)) ? v0 : 0.0;
            acc[7] += (w1 & (1u << 29)) ? v1 : 0.0;
            acc[7] += (w1 & (1u << 30)) ? v2 : 0.0;
            acc[7] += (w1 & (1u << 31)) ? v3 : 0.0;
            w1 = nw;
        }

        if (S > 1) {
            if (slab != 0) {
                #pragma unroll
                for (int j = 0; j < 8; ++j)
                    xch[(slab - 1) * (8 * spb) + j * spb + sl] = acc[j];
            }
            __syncthreads();
            if (slab == 0) {
                for (int s = 1; s < S; ++s)
                    #pragma unroll
                    for (int j = 0; j < 8; ++j)
                        acc[j] += xch[(s - 1) * (8 * spb) + j * spb + sl];
            }
        }

        if (slab == 0) {
            if (isbf) {
                #pragma unroll
                for (int j = 0; j < 8; ++j) {
                    const int t = p * 8 + j;
                    const float z = f64_to_bf16_f32(acc[j]);
                    curF = round_bf16_f32(0.5f * curF + z);
                    volF = round_bf16_f32(0.5f * volF + curF);
                    const bool fire = (volF >= 1.0f);
                    mask |= fire ? (1u << t) : 0u;
                    volF = fire ? 0.f : volF;
                }
            } else {
                #pragma unroll
                for (int j = 0; j < 8; ++j) {
                    const int t = p * 8 + j;
                    curD = fma(0.5, curD, acc[j]);
                    volD = fma(0.5, volD, curD);
                    const bool fire = (volD >= 1.0);
                    mask |= fire ? (1u << t) : 0u;
                    volD = fire ? 0.0 : volD;
                }
            }
        }
        if (S > 1) __syncthreads();              // xch reusable next pass
    }

    if (slab == 0 && valid) {
        cnt = (float)__popc(mask);
        const int gidOut = ((n * COUT + co) * Ho + oh) * Wo + ow;
        if (isbf) {
            uint4* ob = (uint4*)((unsigned short*)goutv + (size_t)gidOut * TT);
            #pragma unroll
            for (int q = 0; q < 4; ++q) {
                unsigned wd[4];
                #pragma unroll
                for (int m2 = 0; m2 < 4; ++m2) {
                    const int t = (q * 4 + m2) * 2;
                    wd[m2] = (((mask >> t) & 1u) ? 0x3F80u : 0u)
                           | (((mask >> (t + 1)) & 1u) ? 0x3F800000u : 0u);
                }
                ob[q] = make_uint4(wd[0], wd[1], wd[2], wd[3]);
            }
        } else {
            float4* ob = (float4*)((float*)goutv + (size_t)gidOut * TT);
            #pragma unroll
            for (int j = 0; j < 8; ++j) {
                float4 s4;
                s4.x = (mask >> (j * 4 + 0)) & 1u ? 1.0f : 0.0f;
                s4.y = (mask >> (j * 4 + 1)) & 1u ? 1.0f : 0.0f;
                s4.z = (mask >> (j * 4 + 2)) & 1u ? 1.0f : 0.0f;
                s4.w = (mask >> (j * 4 + 3)) & 1u ? 1.0f : 0.0f;
                ob[j] = s4;
            }
        }
    }

    #pragma unroll
    for (int o = 32; o >= 1; o >>= 1) cnt += __shfl_down(cnt, o);
    if ((threadIdx.x & 63) == 0 && cnt > 0.f) atomicAdd(sumOut, cnt);
}

__global__ void finalize_counts(const float* __restrict__ sums,
                                void* __restrict__ out, const int* __restrict__ flag)
{
    int i = threadIdx.x;
    if (i < 3) {
        const float numel[3] = {7872512.f, 15239168.f, 3748096.f};
        float v = sums[i] / numel[i];
        if (flag[0]) ((unsigned short*)out)[3748096 + i] = f32_to_bf16_rne(v);
        else         ((float*)out)[3748096 + i] = v;
    }
}

extern "C" void kernel_launch(void* const* d_in, const int* in_sizes, int n_in,
                              void* d_out, int out_size, void* d_ws, size_t ws_size,
                              hipStream_t stream)
{
    const void* x  = d_in[0];  // [4,128,16,16,32] spikes (f32 or bf16)
    const void* w1 = d_in[1];  // [128,64,3,3]
    const void* w2 = d_in[2];  // [64,32,3,3]
    const void* w3 = d_in[3];  // [32,2,3,3]

    // A/B ping-pong (masks in A, index planes in B). Total ws ~ 3.81 MB.
    unsigned* bufA = (unsigned*)d_ws;          // 476,288 words
    unsigned* bufB = bufA + 476288;            // 476,288 words
    unsigned* idx0 = bufB;                     // 131,072 words used
    float* sums = (float*)(bufB + 476288);     // 3 floats
    int*   flag = (int*)(sums + 3);

    detect_and_init<<<1, 64, 0, stream>>>((const unsigned*)x, flag, sums);
    pack_interleave<<<128, 256, 0, stream>>>(x, idx0, flag);

    // Grid: x = site chunk, y = co, z = parity class.
    // L1: 128->64, 16x16 -> 31x31. max class sites 1024 -> x=4
    cuba_layer<128, 64><<<dim3(4, 64, 4), 256, 0, stream>>>(
        idx0, w1, bufA, 4, 16, 16, sums + 0, flag);
    pack_mid<64, 961><<<241, 256, 0, stream>>>(bufA, bufB);
    // L2: 64->32, 31x31 -> 61x61. max class sites 3844 -> x=16
    cuba_layer<64, 32><<<dim3(16, 32, 4), 256, 0, stream>>>(
        bufB, w2, bufA, 4, 31, 31, sums + 1, flag);
    pack_mid<32, 3721><<<466, 256, 0, stream>>>(bufA, bufB);
    // L3: 32->2, 61x61 -> 121x121. S=nTap slabs; heavy: 14400 @64/blk -> x=225
    cuba_layer_slab<32, 2><<<dim3(225, 2, 4), 256, 0, stream>>>(
        bufB, w3, d_out, 4, 61, 61, sums + 2, flag);

    finalize_counts<<<1, 64, 0, stream>>>(sums, d_out, flag);
}

// Round 12
// 383.892 us; speedup vs baseline: 1.3817x; 1.3817x over previous
//
#include <hip/hip_runtime.h>

#define TT 32

// ---------- bf16 helpers (OCP bfloat16, RNE) ----------
__device__ __forceinline__ float bf16_bits_to_f32(unsigned short u) {
    unsigned v = ((unsigned)u) << 16; float f; __builtin_memcpy(&f, &v, 4); return f;
}
__device__ __forceinline__ unsigned short f32_to_bf16_rne(float f) {
    unsigned u; __builtin_memcpy(&u, &f, 4);
    u += 0x7FFFu + ((u >> 16) & 1u);            // round-to-nearest-even
    return (unsigned short)(u >> 16);
}
__device__ __forceinline__ float round_bf16_f32(float f) {  // f32 -> bf16 -> f32 value
    return bf16_bits_to_f32(f32_to_bf16_rne(f));
}
// Correctly-rounded f64 -> bf16 (single rounding): round-to-odd to f32, then RNE.
__device__ __forceinline__ float f64_to_bf16_f32(double d) {
    float fz = __double2float_rz(d);
    if ((double)fz != d) {
        unsigned u; __builtin_memcpy(&u, &fz, 4); u |= 1u; __builtin_memcpy(&fz, &u, 4);
    }
    return round_bf16_f32(fz);
}
// Spread the 8 bits of b to positions 0,4,8,...,28 (Morton-4).
__device__ __forceinline__ unsigned spread4(unsigned b) {
    unsigned x = (b | (b << 12)) & 0x000F000Fu;
    x = (x | (x << 6)) & 0x03030303u;
    x = (x | (x << 3)) & 0x11111111u;
    return x;
}

// ---------- dtype detect + init ----------
__global__ void detect_and_init(const unsigned* __restrict__ spk,
                                int* __restrict__ flag, float* __restrict__ sums)
{
    unsigned w = spk[threadIdx.x];
    bool ok = (w == 0u) || (w == 0x3F800000u);
    unsigned long long vote = __ballot(ok);
    if (threadIdx.x == 0) {
        flag[0] = (vote == 0xFFFFFFFFFFFFFFFFull) ? 0 : 1;  // 0=f32, 1=bf16
        sums[0] = 0.f; sums[1] = 0.f; sums[2] = 0.f;
    }
}

// ---------- layer-0: pack spikes into SoA 4-bit index planes ----------
// Word (q, n,g,site): nibble j = spike bits of t=8q+j across the 4 cins of g.
__global__ __launch_bounds__(256)
void pack_interleave(const void* __restrict__ ginv, unsigned* __restrict__ idx0,
                     const int* __restrict__ flag)
{
    const int gid = blockIdx.x * 256 + threadIdx.x;   // 4*32*256 = 32768
    if (gid >= 32768) return;
    const int site = gid & 255;
    const int g    = (gid >> 8) & 31;
    const int n    = gid >> 13;

    unsigned m[4];
    #pragma unroll
    for (int k = 0; k < 4; ++k) {
        const size_t ebase = ((size_t)(n * 128 + 4 * g + k) * 256 + site) * TT;
        unsigned mask = 0u;
        if (flag[0]) {
            const uint4* p = (const uint4*)((const unsigned short*)ginv + ebase);
            #pragma unroll
            for (int q = 0; q < 4; ++q) {
                uint4 a = p[q];
                unsigned wd[4] = {a.x, a.y, a.z, a.w};
                #pragma unroll
                for (int mm = 0; mm < 4; ++mm) {
                    const int t = q * 8 + mm * 2;
                    mask |= (wd[mm] & 0xFFFFu) ? (1u << t)       : 0u;
                    mask |= (wd[mm] >> 16)     ? (1u << (t + 1)) : 0u;
                }
            }
        } else {
            const float4* p = (const float4*)((const float*)ginv + ebase);
            #pragma unroll
            for (int j = 0; j < 8; ++j) {
                float4 v = p[j];
                mask |= (v.x != 0.f) ? (1u << (j * 4 + 0)) : 0u;
                mask |= (v.y != 0.f) ? (1u << (j * 4 + 1)) : 0u;
                mask |= (v.z != 0.f) ? (1u << (j * 4 + 2)) : 0u;
                mask |= (v.w != 0.f) ? (1u << (j * 4 + 3)) : 0u;
            }
        }
        m[k] = mask;
    }
    #pragma unroll
    for (int q = 0; q < 4; ++q) {
        const unsigned w =  spread4((m[0] >> (8 * q)) & 0xFFu)
                         | (spread4((m[1] >> (8 * q)) & 0xFFu) << 1)
                         | (spread4((m[2] >> (8 * q)) & 0xFFu) << 2)
                         | (spread4((m[3] >> (8 * q)) & 0xFFu) << 3);
        idx0[q * 32768 + gid] = w;
    }
}

// ---------- mid-layer: masks -> SoA 4-bit index planes (plain stores) ----------
template<int C, int PLANE>   // C = channels at this interface
__global__ __launch_bounds__(256)
void pack_mid(const unsigned* __restrict__ masks, unsigned* __restrict__ idx)
{
    constexpr int G = C / 4;
    constexpr int TOT = 4 * G * PLANE;
    const int gid = blockIdx.x * 256 + threadIdx.x;
    if (gid >= TOT) return;
    const int site = gid % PLANE;
    const int g    = (gid / PLANE) % G;
    const int n    = gid / (PLANE * G);
    unsigned m[4];
    #pragma unroll
    for (int k = 0; k < 4; ++k)
        m[k] = masks[(n * C + 4 * g + k) * PLANE + site];
    #pragma unroll
    for (int q = 0; q < 4; ++q) {
        const unsigned w =  spread4((m[0] >> (8 * q)) & 0xFFu)
                         | (spread4((m[1] >> (8 * q)) & 0xFFu) << 1)
                         | (spread4((m[2] >> (8 * q)) & 0xFFu) << 2)
                         | (spread4((m[3] >> (8 * q)) & 0xFFu) << 3);
        idx[q * TOT + gid] = w;
    }
}

// ---------- L1/L2: fused ConvT(stride2,k3,pad1, w*2) + CUBA scan ----------
// R10 structure, but 2 passes of acc[16] (16 independent f64 chains = 2x ILP):
// each pass reads q-planes {2p, 2p+1} (2 b32 loads per (g,tap), prefetched one
// g ahead). __launch_bounds__(256,4) kept -> occupancy unchanged (the R6/R7
// acc-widening regressions were occupancy collapses from dropping it).
template<int CIN, int COUT>
__global__ __launch_bounds__(256, 4)
void cuba_layer(const unsigned* __restrict__ idxIn, const void* __restrict__ wptr,
                unsigned* __restrict__ maskOut, int N, int Hi, int Wi,
                float* __restrict__ sumOut, const int* __restrict__ flag)
{
    constexpr int G = CIN / 4;
    const bool isbf = (flag[0] != 0);
    const int Ho = 2 * Hi - 1, Wo = 2 * Wi - 1;
    const int co = (int)blockIdx.y;
    const int zz = 3 - (int)blockIdx.z;          // heavy class first
    const int po = zz >> 1, pw = zz & 1;
    const int lg = po + pw;
    const int nTap = 1 << lg;
    const int nH = Hi - po, nW = Wi - pw;
    const int sites = N * nH * nW;               // sites in this class (per co)
    const int siteBase = (int)blockIdx.x * 256;
    if (siteBase >= sites) return;               // dead block (uniform)

    // LUT[group][tap][idx]: sequential f64 sum of selected 2*w over the 4 cins.
    __shared__ double lut[G][4][16];
    {
        const unsigned short* w16 = (const unsigned short*)wptr;
        const float* w32 = (const float*)wptr;
        const int entries = G * nTap * 16;
        for (int e = threadIdx.x; e < entries; e += 256) {
            const int idx = e & 15;
            const int tp  = (e >> 4) & (nTap - 1);
            const int g   = e >> (4 + lg);
            const int v = (po && (tp >= (pw ? 2 : 1))) ? 1 : 0;
            const int h = pw ? (tp & 1) : 0;
            const int kh = v ? 0 : (po ? 2 : 1);
            const int kw = h ? 0 : (pw ? 2 : 1);
            const int wof = kh * 3 + kw;
            double s = 0.0;
            #pragma unroll
            for (int k = 0; k < 4; ++k) {
                if ((idx >> k) & 1) {
                    const int wi = ((4 * g + k) * COUT + co) * 9 + wof;
                    const float wraw = isbf ? bf16_bits_to_f32(w16[wi]) : w32[wi];
                    s += 2.0 * (double)wraw;     // weight_scale=2 folded (exact)
                }
            }
            lut[g][tp][idx] = s;
        }
    }
    __syncthreads();

    const int siteIdx = siteBase + (int)threadIdx.x;
    float cnt = 0.f;

    if (siteIdx < sites) {
        const int b  = siteIdx % nW;
        const int t1 = siteIdx / nW;
        const int a  = t1 % nH;
        const int n  = t1 / nH;
        const int oh = 2 * a + po, ow = 2 * b + pw;
        const int plane = Hi * Wi;
        const int QT = N * G * plane;            // words per q-plane

        const int siteA = a * Wi + b;
        const int siteB = siteA + 1;
        const int siteC = siteA + Wi;
        const int siteD = siteC + 1;

        unsigned mask = 0u;
        float  curF = 0.f, volF = 0.f;
        double curD = 0.0, volD = 0.0;

        #pragma unroll 1
        for (int p = 0; p < 2; ++p) {
            double acc[16];
            #pragma unroll
            for (int j = 0; j < 16; ++j) acc[j] = 0.0;

            const unsigned* pb0 = idxIn + (size_t)(2 * p) * QT
                                        + (size_t)(n * G) * plane;
            const unsigned* pb1 = pb0 + QT;

            // Prefetch g=0 idx words (both q-planes).
            unsigned wA0 = pb0[siteA],                wA1 = pb1[siteA];
            unsigned wB0 = pw ? pb0[siteB] : 0u,      wB1 = pw ? pb1[siteB] : 0u;
            unsigned wC0 = po ? pb0[siteC] : 0u,      wC1 = po ? pb1[siteC] : 0u;
            unsigned wD0 = (po && pw) ? pb0[siteD] : 0u,
                     wD1 = (po && pw) ? pb1[siteD] : 0u;

            #pragma unroll 1
            for (int g = 0; g < G; ++g) {
                // Issue next-g loads before consuming current words.
                const size_t off = (size_t)((g + 1 < G) ? g + 1 : g) * plane;
                const unsigned nA0 = pb0[off + siteA], nA1 = pb1[off + siteA];
                const unsigned nB0 = pw ? pb0[off + siteB] : 0u;
                const unsigned nB1 = pw ? pb1[off + siteB] : 0u;
                const unsigned nC0 = po ? pb0[off + siteC] : 0u;
                const unsigned nC1 = po ? pb1[off + siteC] : 0u;
                const unsigned nD0 = (po && pw) ? pb0[off + siteD] : 0u;
                const unsigned nD1 = (po && pw) ? pb1[off + siteD] : 0u;

                auto tapWork = [&](unsigned w0, unsigned w1, int tp) {
                    const double* lp = &lut[g][tp][0];
                    #pragma unroll
                    for (int j = 0; j < 8; ++j)
                        acc[j] += lp[(w0 >> (4 * j)) & 0xFu];
                    #pragma unroll
                    for (int j = 0; j < 8; ++j)
                        acc[8 + j] += lp[(w1 >> (4 * j)) & 0xFu];
                };

                tapWork(wA0, wA1, 0);
                if (pw) tapWork(wB0, wB1, 1);    // block-uniform branches
                if (po) {
                    tapWork(wC0, wC1, pw ? 2 : 1);
                    if (pw) tapWork(wD0, wD1, 3);
                }

                wA0 = nA0; wA1 = nA1; wB0 = nB0; wB1 = nB1;
                wC0 = nC0; wC1 = nC1; wD0 = nD0; wD1 = nD1;
            }

            // CUBA scan, 16 steps with carried state.
            if (isbf) {
                #pragma unroll
                for (int j = 0; j < 16; ++j) {
                    const int t = p * 16 + j;
                    const float z = f64_to_bf16_f32(acc[j]);
                    curF = round_bf16_f32(0.5f * curF + z);
                    volF = round_bf16_f32(0.5f * volF + curF);
                    const bool fire = (volF >= 1.0f);
                    mask |= fire ? (1u << t) : 0u;
                    volF = fire ? 0.f : volF;
                }
            } else {
                #pragma unroll
                for (int j = 0; j < 16; ++j) {
                    const int t = p * 16 + j;
                    curD = fma(0.5, curD, acc[j]);
                    volD = fma(0.5, volD, curD);
                    const bool fire = (volD >= 1.0);
                    mask |= fire ? (1u << t) : 0u;
                    volD = fire ? 0.0 : volD;
                }
            }
        }
        cnt = (float)__popc(mask);
        maskOut[((n * COUT + co) * Ho + oh) * Wo + ow] = mask;
    }

    // Wave-level (64) count reduction; per-layer sums are integers < 2^24 so
    // fp32 atomic accumulation is exact.
    #pragma unroll
    for (int o = 32; o >= 1; o >>= 1) cnt += __shfl_down(cnt, o);
    if ((threadIdx.x & 63) == 0 && cnt > 0.f) atomicAdd(sumOut, cnt);
}

// ---------- L3: tap-slab kernel (S = nTap slabs, LDS combine) + prefetch ----------
template<int CIN, int COUT>
__global__ __launch_bounds__(256)
void cuba_layer_slab(const unsigned* __restrict__ idxIn, const void* __restrict__ wptr,
                     void* __restrict__ goutv, int N, int Hi, int Wi,
                     float* __restrict__ sumOut, const int* __restrict__ flag)
{
    constexpr int G = CIN / 4;
    const bool isbf = (flag[0] != 0);
    const int Ho = 2 * Hi - 1, Wo = 2 * Wi - 1;
    const int co = (int)blockIdx.y;
    const int zz = 3 - (int)blockIdx.z;          // heavy class first
    const int po = zz >> 1, pw = zz & 1;
    const int lg = po + pw;
    const int nTap = 1 << lg;
    const int nH = Hi - po, nW = Wi - pw;
    const int sites = N * nH * nW;
    const int lS = lg;
    const int S  = 1 << lS;                      // slabs per block (== nTap)
    const int spb = 256 >> lS;                   // sites per block
    const int siteBase = (int)blockIdx.x * spb;
    if (siteBase >= sites) return;               // dead block (uniform)

    __shared__ double lut[G][4][16];
    __shared__ double xch[1536];                 // slab-partial exchange
    {
        const unsigned short* w16 = (const unsigned short*)wptr;
        const float* w32 = (const float*)wptr;
        const int entries = G * nTap * 16;
        for (int e = threadIdx.x; e < entries; e += 256) {
            const int idx = e & 15;
            const int tp  = (e >> 4) & (nTap - 1);
            const int g   = e >> (4 + lg);
            const int v = (po && (tp >= (pw ? 2 : 1))) ? 1 : 0;
            const int h = pw ? (tp & 1) : 0;
            const int kh = v ? 0 : (po ? 2 : 1);
            const int kw = h ? 0 : (pw ? 2 : 1);
            const int wof = kh * 3 + kw;
            double s = 0.0;
            #pragma unroll
            for (int k = 0; k < 4; ++k) {
                if ((idx >> k) & 1) {
                    const int wi = ((4 * g + k) * COUT + co) * 9 + wof;
                    const float wraw = isbf ? bf16_bits_to_f32(w16[wi]) : w32[wi];
                    s += 2.0 * (double)wraw;
                }
            }
            lut[g][tp][idx] = s;
        }
    }
    __syncthreads();

    const int slab = (int)threadIdx.x >> (8 - lS);
    const int sl   = (int)threadIdx.x & (spb - 1);
    const int siteIdx = siteBase + sl;
    const bool valid = siteIdx < sites;
    const int sIdx = valid ? siteIdx : 0;        // clamp for safe addresses

    const int b  = sIdx % nW;
    const int t1v = sIdx / nW;
    const int a  = t1v % nH;
    const int n  = t1v / nH;
    const int oh = 2 * a + po, ow = 2 * b + pw;
    const int plane = Hi * Wi;
    const int QT = N * G * plane;                // words per q-plane (SoA)

    const int siteA = a * Wi + b;
    const int siteB = siteA + 1;
    const int siteC = siteA + Wi;
    const int siteD = siteC + 1;

    // Per-thread tap assignment (wave-uniform).
    int s1 = siteA, tp1 = 0;
    if (zz == 1)      { if (slab == 1) { s1 = siteB; tp1 = 1; } }
    else if (zz == 2) { if (slab == 1) { s1 = siteC; tp1 = 1; } }
    else if (zz == 3) {
        if      (slab == 1) { s1 = siteB; tp1 = 1; }
        else if (slab == 2) { s1 = siteC; tp1 = 2; }
        else if (slab == 3) { s1 = siteD; tp1 = 3; }
    }

    unsigned mask = 0u;
    float  curF = 0.f, volF = 0.f;
    double curD = 0.0, volD = 0.0;
    float cnt = 0.f;

    #pragma unroll 1
    for (int p = 0; p < 4; ++p) {
        double acc[8];
        #pragma unroll
        for (int j = 0; j < 8; ++j) acc[j] = 0.0;

        const unsigned* pb = idxIn + (size_t)p * QT + (size_t)(n * G) * plane;

        unsigned w1 = pb[s1];                    // prefetch g=0
        #pragma unroll 1
        for (int g = 0; g < G; ++g) {
            const unsigned nw =
                pb[(size_t)((g + 1 < G) ? g + 1 : g) * plane + s1];
            #pragma unroll
            for (int j = 0; j < 8; ++j)
                acc[j] += lut[g][tp1][(w1 >> (4 * j)) & 0xFu];
            w1 = nw;
        }

        if (S > 1) {
            if (slab != 0) {
                #pragma unroll
                for (int j = 0; j < 8; ++j)
                    xch[(slab - 1) * (8 * spb) + j * spb + sl] = acc[j];
            }
            __syncthreads();
            if (slab == 0) {
                for (int s = 1; s < S; ++s)
                    #pragma unroll
                    for (int j = 0; j < 8; ++j)
                        acc[j] += xch[(s - 1) * (8 * spb) + j * spb + sl];
            }
        }

        if (slab == 0) {
            if (isbf) {
                #pragma unroll
                for (int j = 0; j < 8; ++j) {
                    const int t = p * 8 + j;
                    const float z = f64_to_bf16_f32(acc[j]);
                    curF = round_bf16_f32(0.5f * curF + z);
                    volF = round_bf16_f32(0.5f * volF + curF);
                    const bool fire = (volF >= 1.0f);
                    mask |= fire ? (1u << t) : 0u;
                    volF = fire ? 0.f : volF;
                }
            } else {
                #pragma unroll
                for (int j = 0; j < 8; ++j) {
                    const int t = p * 8 + j;
                    curD = fma(0.5, curD, acc[j]);
                    volD = fma(0.5, volD, curD);
                    const bool fire = (volD >= 1.0);
                    mask |= fire ? (1u << t) : 0u;
                    volD = fire ? 0.0 : volD;
                }
            }
        }
        if (S > 1) __syncthreads();              // xch reusable next pass
    }

    if (slab == 0 && valid) {
        cnt = (float)__popc(mask);
        const int gidOut = ((n * COUT + co) * Ho + oh) * Wo + ow;
        if (isbf) {
            uint4* ob = (uint4*)((unsigned short*)goutv + (size_t)gidOut * TT);
            #pragma unroll
            for (int q = 0; q < 4; ++q) {
                unsigned wd[4];
                #pragma unroll
                for (int m2 = 0; m2 < 4; ++m2) {
                    const int t = (q * 4 + m2) * 2;
                    wd[m2] = (((mask >> t) & 1u) ? 0x3F80u : 0u)
                           | (((mask >> (t + 1)) & 1u) ? 0x3F800000u : 0u);
                }
                ob[q] = make_uint4(wd[0], wd[1], wd[2], wd[3]);
            }
        } else {
            float4* ob = (float4*)((float*)goutv + (size_t)gidOut * TT);
            #pragma unroll
            for (int j = 0; j < 8; ++j) {
                float4 s4;
                s4.x = (mask >> (j * 4 + 0)) & 1u ? 1.0f : 0.0f;
                s4.y = (mask >> (j * 4 + 1)) & 1u ? 1.0f : 0.0f;
                s4.z = (mask >> (j * 4 + 2)) & 1u ? 1.0f : 0.0f;
                s4.w = (mask >> (j * 4 + 3)) & 1u ? 1.0f : 0.0f;
                ob[j] = s4;
            }
        }
    }

    #pragma unroll
    for (int o = 32; o >= 1; o >>= 1) cnt += __shfl_down(cnt, o);
    if ((threadIdx.x & 63) == 0 && cnt > 0.f) atomicAdd(sumOut, cnt);
}

__global__ void finalize_counts(const float* __restrict__ sums,
                                void* __restrict__ out, const int* __restrict__ flag)
{
    int i = threadIdx.x;
    if (i < 3) {
        const float numel[3] = {7872512.f, 15239168.f, 3748096.f};
        float v = sums[i] / numel[i];
        if (flag[0]) ((unsigned short*)out)[3748096 + i] = f32_to_bf16_rne(v);
        else         ((float*)out)[3748096 + i] = v;
    }
}

extern "C" void kernel_launch(void* const* d_in, const int* in_sizes, int n_in,
                              void* d_out, int out_size, void* d_ws, size_t ws_size,
                              hipStream_t stream)
{
    const void* x  = d_in[0];  // [4,128,16,16,32] spikes (f32 or bf16)
    const void* w1 = d_in[1];  // [128,64,3,3]
    const void* w2 = d_in[2];  // [64,32,3,3]
    const void* w3 = d_in[3];  // [32,2,3,3]

    // A/B ping-pong (masks in A, index planes in B). Total ws ~ 3.81 MB.
    unsigned* bufA = (unsigned*)d_ws;          // 476,288 words
    unsigned* bufB = bufA + 476288;            // 476,288 words
    unsigned* idx0 = bufB;                     // 131,072 words used
    float* sums = (float*)(bufB + 476288);     // 3 floats
    int*   flag = (int*)(sums + 3);

    detect_and_init<<<1, 64, 0, stream>>>((const unsigned*)x, flag, sums);
    pack_interleave<<<128, 256, 0, stream>>>(x, idx0, flag);

    // Grid: x = site chunk, y = co, z = parity class.
    // L1: 128->64, 16x16 -> 31x31. max class sites 1024 -> x=4
    cuba_layer<128, 64><<<dim3(4, 64, 4), 256, 0, stream>>>(
        idx0, w1, bufA, 4, 16, 16, sums + 0, flag);
    pack_mid<64, 961><<<241, 256, 0, stream>>>(bufA, bufB);
    // L2: 64->32, 31x31 -> 61x61. max class sites 3844 -> x=16
    cuba_layer<64, 32><<<dim3(16, 32, 4), 256, 0, stream>>>(
        bufB, w2, bufA, 4, 31, 31, sums + 1, flag);
    pack_mid<32, 3721><<<466, 256, 0, stream>>>(bufA, bufB);
    // L3: 32->2, 61x61 -> 121x121. S=nTap slabs; heavy: 14400 @64/blk -> x=225
    cuba_layer_slab<32, 2><<<dim3(225, 2, 4), 256, 0, stream>>>(
        bufB, w3, d_out, 4, 61, 61, sums + 2, flag);

    finalize_counts<<<1, 64, 0, stream>>>(sums, d_out, flag);
}

// Round 13
// 370.371 us; speedup vs baseline: 1.4321x; 1.0365x over previous
//
#include <hip/hip_runtime.h>

#define TT 32

// ---------- bf16 helpers (OCP bfloat16, RNE) ----------
__device__ __forceinline__ float bf16_bits_to_f32(unsigned short u) {
    unsigned v = ((unsigned)u) << 16; float f; __builtin_memcpy(&f, &v, 4); return f;
}
__device__ __forceinline__ unsigned short f32_to_bf16_rne(float f) {
    unsigned u; __builtin_memcpy(&u, &f, 4);
    u += 0x7FFFu + ((u >> 16) & 1u);            // round-to-nearest-even
    return (unsigned short)(u >> 16);
}
__device__ __forceinline__ float round_bf16_f32(float f) {  // f32 -> bf16 -> f32 value
    return bf16_bits_to_f32(f32_to_bf16_rne(f));
}
// Correctly-rounded f64 -> bf16 (single rounding): round-to-odd to f32, then RNE.
__device__ __forceinline__ float f64_to_bf16_f32(double d) {
    float fz = __double2float_rz(d);
    if ((double)fz != d) {
        unsigned u; __builtin_memcpy(&u, &fz, 4); u |= 1u; __builtin_memcpy(&fz, &u, 4);
    }
    return round_bf16_f32(fz);
}
// Spread the 8 bits of b to positions 0,4,8,...,28 (Morton-4).
__device__ __forceinline__ unsigned spread4(unsigned b) {
    unsigned x = (b | (b << 12)) & 0x000F000Fu;
    x = (x | (x << 6)) & 0x03030303u;
    x = (x | (x << 3)) & 0x11111111u;
    return x;
}

// ---------- dtype detect + init ----------
__global__ void detect_and_init(const unsigned* __restrict__ spk,
                                int* __restrict__ flag, float* __restrict__ sums)
{
    unsigned w = spk[threadIdx.x];
    bool ok = (w == 0u) || (w == 0x3F800000u);
    unsigned long long vote = __ballot(ok);
    if (threadIdx.x == 0) {
        flag[0] = (vote == 0xFFFFFFFFFFFFFFFFull) ? 0 : 1;  // 0=f32, 1=bf16
        sums[0] = 0.f; sums[1] = 0.f; sums[2] = 0.f;
    }
}

// ---------- layer-0: pack spikes into SoA 4-bit index planes ----------
// Word (q, n,g,site): nibble j = spike bits of t=8q+j across the 4 cins of g.
__global__ __launch_bounds__(256)
void pack_interleave(const void* __restrict__ ginv, unsigned* __restrict__ idx0,
                     const int* __restrict__ flag)
{
    const int gid = blockIdx.x * 256 + threadIdx.x;   // 4*32*256 = 32768
    if (gid >= 32768) return;
    const int site = gid & 255;
    const int g    = (gid >> 8) & 31;
    const int n    = gid >> 13;

    unsigned m[4];
    #pragma unroll
    for (int k = 0; k < 4; ++k) {
        const size_t ebase = ((size_t)(n * 128 + 4 * g + k) * 256 + site) * TT;
        unsigned mask = 0u;
        if (flag[0]) {
            const uint4* p = (const uint4*)((const unsigned short*)ginv + ebase);
            #pragma unroll
            for (int q = 0; q < 4; ++q) {
                uint4 a = p[q];
                unsigned wd[4] = {a.x, a.y, a.z, a.w};
                #pragma unroll
                for (int mm = 0; mm < 4; ++mm) {
                    const int t = q * 8 + mm * 2;
                    mask |= (wd[mm] & 0xFFFFu) ? (1u << t)       : 0u;
                    mask |= (wd[mm] >> 16)     ? (1u << (t + 1)) : 0u;
                }
            }
        } else {
            const float4* p = (const float4*)((const float*)ginv + ebase);
            #pragma unroll
            for (int j = 0; j < 8; ++j) {
                float4 v = p[j];
                mask |= (v.x != 0.f) ? (1u << (j * 4 + 0)) : 0u;
                mask |= (v.y != 0.f) ? (1u << (j * 4 + 1)) : 0u;
                mask |= (v.z != 0.f) ? (1u << (j * 4 + 2)) : 0u;
                mask |= (v.w != 0.f) ? (1u << (j * 4 + 3)) : 0u;
            }
        }
        m[k] = mask;
    }
    #pragma unroll
    for (int q = 0; q < 4; ++q) {
        const unsigned w =  spread4((m[0] >> (8 * q)) & 0xFFu)
                         | (spread4((m[1] >> (8 * q)) & 0xFFu) << 1)
                         | (spread4((m[2] >> (8 * q)) & 0xFFu) << 2)
                         | (spread4((m[3] >> (8 * q)) & 0xFFu) << 3);
        idx0[q * 32768 + gid] = w;
    }
}

// ---------- mid-layer: masks -> SoA 4-bit index planes (plain stores) ----------
template<int C, int PLANE>   // C = channels at this interface
__global__ __launch_bounds__(256)
void pack_mid(const unsigned* __restrict__ masks, unsigned* __restrict__ idx)
{
    constexpr int G = C / 4;
    constexpr int TOT = 4 * G * PLANE;
    const int gid = blockIdx.x * 256 + threadIdx.x;
    if (gid >= TOT) return;
    const int site = gid % PLANE;
    const int g    = (gid / PLANE) % G;
    const int n    = gid / (PLANE * G);
    unsigned m[4];
    #pragma unroll
    for (int k = 0; k < 4; ++k)
        m[k] = masks[(n * C + 4 * g + k) * PLANE + site];
    #pragma unroll
    for (int q = 0; q < 4; ++q) {
        const unsigned w =  spread4((m[0] >> (8 * q)) & 0xFFu)
                         | (spread4((m[1] >> (8 * q)) & 0xFFu) << 1)
                         | (spread4((m[2] >> (8 * q)) & 0xFFu) << 2)
                         | (spread4((m[3] >> (8 * q)) & 0xFFu) << 3);
        idx[q * TOT + gid] = w;
    }
}

// ---------- L1/L2: fused ConvT(stride2,k3,pad1, w*2) + CUBA scan ----------
// Verified-best structure (R10): thread = site, g loop-uniform, tap
// block-uniform -> wave reads <=16 distinct LUT entries (broadcast,
// conflict-free). t in 4 passes of acc[8] (best ILP/occupancy trade across
// R6/R7/R12 tests); next-g prefetch hides the L2 idx-load latency.
template<int CIN, int COUT>
__global__ __launch_bounds__(256, 4)
void cuba_layer(const unsigned* __restrict__ idxIn, const void* __restrict__ wptr,
                unsigned* __restrict__ maskOut, int N, int Hi, int Wi,
                float* __restrict__ sumOut, const int* __restrict__ flag)
{
    constexpr int G = CIN / 4;
    const bool isbf = (flag[0] != 0);
    const int Ho = 2 * Hi - 1, Wo = 2 * Wi - 1;
    const int co = (int)blockIdx.y;
    const int zz = 3 - (int)blockIdx.z;          // heavy class first
    const int po = zz >> 1, pw = zz & 1;
    const int lg = po + pw;
    const int nTap = 1 << lg;
    const int nH = Hi - po, nW = Wi - pw;
    const int sites = N * nH * nW;               // sites in this class (per co)
    const int siteBase = (int)blockIdx.x * 256;
    if (siteBase >= sites) return;               // dead block (uniform)

    // LUT[group][tap][idx]: sequential f64 sum of selected 2*w over the 4 cins.
    __shared__ double lut[G][4][16];
    {
        const unsigned short* w16 = (const unsigned short*)wptr;
        const float* w32 = (const float*)wptr;
        const int entries = G * nTap * 16;
        for (int e = threadIdx.x; e < entries; e += 256) {
            const int idx = e & 15;
            const int tp  = (e >> 4) & (nTap - 1);
            const int g   = e >> (4 + lg);
            const int v = (po && (tp >= (pw ? 2 : 1))) ? 1 : 0;
            const int h = pw ? (tp & 1) : 0;
            const int kh = v ? 0 : (po ? 2 : 1);
            const int kw = h ? 0 : (pw ? 2 : 1);
            const int wof = kh * 3 + kw;
            double s = 0.0;
            #pragma unroll
            for (int k = 0; k < 4; ++k) {
                if ((idx >> k) & 1) {
                    const int wi = ((4 * g + k) * COUT + co) * 9 + wof;
                    const float wraw = isbf ? bf16_bits_to_f32(w16[wi]) : w32[wi];
                    s += 2.0 * (double)wraw;     // weight_scale=2 folded (exact)
                }
            }
            lut[g][tp][idx] = s;
        }
    }
    __syncthreads();

    const int siteIdx = siteBase + (int)threadIdx.x;
    float cnt = 0.f;

    if (siteIdx < sites) {
        const int b  = siteIdx % nW;
        const int t1 = siteIdx / nW;
        const int a  = t1 % nH;
        const int n  = t1 / nH;
        const int oh = 2 * a + po, ow = 2 * b + pw;
        const int plane = Hi * Wi;
        const int QT = N * G * plane;            // words per q-plane

        const int siteA = a * Wi + b;
        const int siteB = siteA + 1;
        const int siteC = siteA + Wi;
        const int siteD = siteC + 1;

        unsigned mask = 0u;
        float  curF = 0.f, volF = 0.f;
        double curD = 0.0, volD = 0.0;

        #pragma unroll 1
        for (int p = 0; p < 4; ++p) {
            double acc[8];
            #pragma unroll
            for (int j = 0; j < 8; ++j) acc[j] = 0.0;

            const unsigned* pb = idxIn + (size_t)p * QT + (size_t)(n * G) * plane;

            // Prefetch g=0 idx words.
            unsigned wA = pb[siteA];
            unsigned wB = pw ? pb[siteB] : 0u;
            unsigned wC = po ? pb[siteC] : 0u;
            unsigned wD = (po && pw) ? pb[siteD] : 0u;

            #pragma unroll 1
            for (int g = 0; g < G; ++g) {
                // Issue next-g loads before consuming current words.
                const unsigned* bpn = pb + (size_t)((g + 1 < G) ? g + 1 : g) * plane;
                const unsigned nA = bpn[siteA];
                const unsigned nB = pw ? bpn[siteB] : 0u;
                const unsigned nC = po ? bpn[siteC] : 0u;
                const unsigned nD = (po && pw) ? bpn[siteD] : 0u;

                {
                    #pragma unroll
                    for (int j = 0; j < 8; ++j)
                        acc[j] += lut[g][0][(wA >> (4 * j)) & 0xFu];
                }
                if (pw) {
                    #pragma unroll
                    for (int j = 0; j < 8; ++j)
                        acc[j] += lut[g][1][(wB >> (4 * j)) & 0xFu];
                }
                if (po) {
                    #pragma unroll
                    for (int j = 0; j < 8; ++j)
                        acc[j] += lut[g][pw ? 2 : 1][(wC >> (4 * j)) & 0xFu];
                }
                if (po && pw) {
                    #pragma unroll
                    for (int j = 0; j < 8; ++j)
                        acc[j] += lut[g][3][(wD >> (4 * j)) & 0xFu];
                }

                wA = nA; wB = nB; wC = nC; wD = nD;
            }

            // CUBA scan, 8 steps with carried state.
            if (isbf) {
                #pragma unroll
                for (int j = 0; j < 8; ++j) {
                    const int t = p * 8 + j;
                    const float z = f64_to_bf16_f32(acc[j]);
                    curF = round_bf16_f32(0.5f * curF + z);
                    volF = round_bf16_f32(0.5f * volF + curF);
                    const bool fire = (volF >= 1.0f);
                    mask |= fire ? (1u << t) : 0u;
                    volF = fire ? 0.f : volF;
                }
            } else {
                #pragma unroll
                for (int j = 0; j < 8; ++j) {
                    const int t = p * 8 + j;
                    curD = fma(0.5, curD, acc[j]);
                    volD = fma(0.5, volD, curD);
                    const bool fire = (volD >= 1.0);
                    mask |= fire ? (1u << t) : 0u;
                    volD = fire ? 0.0 : volD;
                }
            }
        }
        cnt = (float)__popc(mask);
        maskOut[((n * COUT + co) * Ho + oh) * Wo + ow] = mask;
    }

    // Wave-level (64) count reduction; per-layer sums are integers < 2^24 so
    // fp32 atomic accumulation is exact.
    #pragma unroll
    for (int o = 32; o >= 1; o >>= 1) cnt += __shfl_down(cnt, o);
    if ((threadIdx.x & 63) == 0 && cnt > 0.f) atomicAdd(sumOut, cnt);
}

// ---------- L3: tap-slab kernel (S = nTap slabs, LDS combine) + prefetch ----------
template<int CIN, int COUT>
__global__ __launch_bounds__(256)
void cuba_layer_slab(const unsigned* __restrict__ idxIn, const void* __restrict__ wptr,
                     void* __restrict__ goutv, int N, int Hi, int Wi,
                     float* __restrict__ sumOut, const int* __restrict__ flag)
{
    constexpr int G = CIN / 4;
    const bool isbf = (flag[0] != 0);
    const int Ho = 2 * Hi - 1, Wo = 2 * Wi - 1;
    const int co = (int)blockIdx.y;
    const int zz = 3 - (int)blockIdx.z;          // heavy class first
    const int po = zz >> 1, pw = zz & 1;
    const int lg = po + pw;
    const int nTap = 1 << lg;
    const int nH = Hi - po, nW = Wi - pw;
    const int sites = N * nH * nW;
    const int lS = lg;
    const int S  = 1 << lS;                      // slabs per block (== nTap)
    const int spb = 256 >> lS;                   // sites per block
    const int siteBase = (int)blockIdx.x * spb;
    if (siteBase >= sites) return;               // dead block (uniform)

    __shared__ double lut[G][4][16];
    __shared__ double xch[1536];                 // slab-partial exchange
    {
        const unsigned short* w16 = (const unsigned short*)wptr;
        const float* w32 = (const float*)wptr;
        const int entries = G * nTap * 16;
        for (int e = threadIdx.x; e < entries; e += 256) {
            const int idx = e & 15;
            const int tp  = (e >> 4) & (nTap - 1);
            const int g   = e >> (4 + lg);
            const int v = (po && (tp >= (pw ? 2 : 1))) ? 1 : 0;
            const int h = pw ? (tp & 1) : 0;
            const int kh = v ? 0 : (po ? 2 : 1);
            const int kw = h ? 0 : (pw ? 2 : 1);
            const int wof = kh * 3 + kw;
            double s = 0.0;
            #pragma unroll
            for (int k = 0; k < 4; ++k) {
                if ((idx >> k) & 1) {
                    const int wi = ((4 * g + k) * COUT + co) * 9 + wof;
                    const float wraw = isbf ? bf16_bits_to_f32(w16[wi]) : w32[wi];
                    s += 2.0 * (double)wraw;
                }
            }
            lut[g][tp][idx] = s;
        }
    }
    __syncthreads();

    const int slab = (int)threadIdx.x >> (8 - lS);
    const int sl   = (int)threadIdx.x & (spb - 1);
    const int siteIdx = siteBase + sl;
    const bool valid = siteIdx < sites;
    const int sIdx = valid ? siteIdx : 0;        // clamp for safe addresses

    const int b  = sIdx % nW;
    const int t1v = sIdx / nW;
    const int a  = t1v % nH;
    const int n  = t1v / nH;
    const int oh = 2 * a + po, ow = 2 * b + pw;
    const int plane = Hi * Wi;
    const int QT = N * G * plane;                // words per q-plane (SoA)

    const int siteA = a * Wi + b;
    const int siteB = siteA + 1;
    const int siteC = siteA + Wi;
    const int siteD = siteC + 1;

    // Per-thread tap assignment (wave-uniform).
    int s1 = siteA, tp1 = 0;
    if (zz == 1)      { if (slab == 1) { s1 = siteB; tp1 = 1; } }
    else if (zz == 2) { if (slab == 1) { s1 = siteC; tp1 = 1; } }
    else if (zz == 3) {
        if      (slab == 1) { s1 = siteB; tp1 = 1; }
        else if (slab == 2) { s1 = siteC; tp1 = 2; }
        else if (slab == 3) { s1 = siteD; tp1 = 3; }
    }

    unsigned mask = 0u;
    float  curF = 0.f, volF = 0.f;
    double curD = 0.0, volD = 0.0;
    float cnt = 0.f;

    #pragma unroll 1
    for (int p = 0; p < 4; ++p) {
        double acc[8];
        #pragma unroll
        for (int j = 0; j < 8; ++j) acc[j] = 0.0;

        const unsigned* pb = idxIn + (size_t)p * QT + (size_t)(n * G) * plane;

        unsigned w1 = pb[s1];                    // prefetch g=0
        #pragma unroll 1
        for (int g = 0; g < G; ++g) {
            const unsigned nw =
                pb[(size_t)((g + 1 < G) ? g + 1 : g) * plane + s1];
            #pragma unroll
            for (int j = 0; j < 8; ++j)
                acc[j] += lut[g][tp1][(w1 >> (4 * j)) & 0xFu];
            w1 = nw;
        }

        if (S > 1) {
            if (slab != 0) {
                #pragma unroll
                for (int j = 0; j < 8; ++j)
                    xch[(slab - 1) * (8 * spb) + j * spb + sl] = acc[j];
            }
            __syncthreads();
            if (slab == 0) {
                for (int s = 1; s < S; ++s)
                    #pragma unroll
                    for (int j = 0; j < 8; ++j)
                        acc[j] += xch[(s - 1) * (8 * spb) + j * spb + sl];
            }
        }

        if (slab == 0) {
            if (isbf) {
                #pragma unroll
                for (int j = 0; j < 8; ++j) {
                    const int t = p * 8 + j;
                    const float z = f64_to_bf16_f32(acc[j]);
                    curF = round_bf16_f32(0.5f * curF + z);
                    volF = round_bf16_f32(0.5f * volF + curF);
                    const bool fire = (volF >= 1.0f);
                    mask |= fire ? (1u << t) : 0u;
                    volF = fire ? 0.f : volF;
                }
            } else {
                #pragma unroll
                for (int j = 0; j < 8; ++j) {
                    const int t = p * 8 + j;
                    curD = fma(0.5, curD, acc[j]);
                    volD = fma(0.5, volD, curD);
                    const bool fire = (volD >= 1.0);
                    mask |= fire ? (1u << t) : 0u;
                    volD = fire ? 0.0 : volD;
                }
            }
        }
        if (S > 1) __syncthreads();              // xch reusable next pass
    }

    if (slab == 0 && valid) {
        cnt = (float)__popc(mask);
        const int gidOut = ((n * COUT + co) * Ho + oh) * Wo + ow;
        if (isbf) {
            uint4* ob = (uint4*)((unsigned short*)goutv + (size_t)gidOut * TT);
            #pragma unroll
            for (int q = 0; q < 4; ++q) {
                unsigned wd[4];
                #pragma unroll
                for (int m2 = 0; m2 < 4; ++m2) {
                    const int t = (q * 4 + m2) * 2;
                    wd[m2] = (((mask >> t) & 1u) ? 0x3F80u : 0u)
                           | (((mask >> (t + 1)) & 1u) ? 0x3F800000u : 0u);
                }
                ob[q] = make_uint4(wd[0], wd[1], wd[2], wd[3]);
            }
        } else {
            float4* ob = (float4*)((float*)goutv + (size_t)gidOut * TT);
            #pragma unroll
            for (int j = 0; j < 8; ++j) {
                float4 s4;
                s4.x = (mask >> (j * 4 + 0)) & 1u ? 1.0f : 0.0f;
                s4.y = (mask >> (j * 4 + 1)) & 1u ? 1.0f : 0.0f;
                s4.z = (mask >> (j * 4 + 2)) & 1u ? 1.0f : 0.0f;
                s4.w = (mask >> (j * 4 + 3)) & 1u ? 1.0f : 0.0f;
                ob[j] = s4;
            }
        }
    }

    #pragma unroll
    for (int o = 32; o >= 1; o >>= 1) cnt += __shfl_down(cnt, o);
    if ((threadIdx.x & 63) == 0 && cnt > 0.f) atomicAdd(sumOut, cnt);
}

__global__ void finalize_counts(const float* __restrict__ sums,
                                void* __restrict__ out, const int* __restrict__ flag)
{
    int i = threadIdx.x;
    if (i < 3) {
        const float numel[3] = {7872512.f, 15239168.f, 3748096.f};
        float v = sums[i] / numel[i];
        if (flag[0]) ((unsigned short*)out)[3748096 + i] = f32_to_bf16_rne(v);
        else         ((float*)out)[3748096 + i] = v;
    }
}

extern "C" void kernel_launch(void* const* d_in, const int* in_sizes, int n_in,
                              void* d_out, int out_size, void* d_ws, size_t ws_size,
                              hipStream_t stream)
{
    const void* x  = d_in[0];  // [4,128,16,16,32] spikes (f32 or bf16)
    const void* w1 = d_in[1];  // [128,64,3,3]
    const void* w2 = d_in[2];  // [64,32,3,3]
    const void* w3 = d_in[3];  // [32,2,3,3]

    // A/B ping-pong (masks in A, index planes in B). Total ws ~ 3.81 MB.
    unsigned* bufA = (unsigned*)d_ws;          // 476,288 words
    unsigned* bufB = bufA + 476288;            // 476,288 words
    unsigned* idx0 = bufB;                     // 131,072 words used
    float* sums = (float*)(bufB + 476288);     // 3 floats
    int*   flag = (int*)(sums + 3);

    detect_and_init<<<1, 64, 0, stream>>>((const unsigned*)x, flag, sums);
    pack_interleave<<<128, 256, 0, stream>>>(x, idx0, flag);

    // Grid: x = site chunk, y = co, z = parity class.
    // L1: 128->64, 16x16 -> 31x31. max class sites 1024 -> x=4
    cuba_layer<128, 64><<<dim3(4, 64, 4), 256, 0, stream>>>(
        idx0, w1, bufA, 4, 16, 16, sums + 0, flag);
    pack_mid<64, 961><<<241, 256, 0, stream>>>(bufA, bufB);
    // L2: 64->32, 31x31 -> 61x61. max class sites 3844 -> x=16
    cuba_layer<64, 32><<<dim3(16, 32, 4), 256, 0, stream>>>(
        bufB, w2, bufA, 4, 31, 31, sums + 1, flag);
    pack_mid<32, 3721><<<466, 256, 0, stream>>>(bufA, bufB);
    // L3: 32->2, 61x61 -> 121x121. S=nTap slabs; heavy: 14400 @64/blk -> x=225
    cuba_layer_slab<32, 2><<<dim3(225, 2, 4), 256, 0, stream>>>(
        bufB, w3, d_out, 4, 61, 61, sums + 2, flag);

    finalize_counts<<<1, 64, 0, stream>>>(sums, d_out, flag);
}